// Round 1
// baseline (129.132 us; speedup 1.0000x reference)
//
#include <hip/hip_runtime.h>
#include <hip/hip_cooperative_groups.h>

namespace cg = cooperative_groups;

// CenterLoss, exact masked shortcut:
//   out = mean_i clip(0.5*(||x_i||^2 + ||c_{l_i}||^2) + 0.3 * x_i . c_{l_i}, 1e-12, 1e12)
//         + (C-1)*1e-12          // the B*(C-1) masked-out zeros, each clipped to 1e-12
// B=4096, C=10000, D=512 (fp32 inputs, int32 labels, fp32 scalar output)
//
// Round-2 structure: ONE cooperative kernel (was 2 nodes). dur_us is dominated
// by the harness's 2x256MiB d_ws poison fills (~68-70 us overlapped); our job
// is to minimize the serial tail after them. k2 was a latency-only node (8 KiB
// read) — fused behind a grid.sync() instead.
//   phase 1: 1024 blocks x 256 thr, 1 wave per row -> partial[blockIdx]
//            (plain store, overwrites the 0xAA poison, no memset needed)
//   grid.sync()  (1024 blocks = 4/CU at ~24 VGPR -> co-residency guaranteed)
//   phase 2: block 0 reduces 1024 partials -> out scalar

constexpr int BATCH = 4096;
constexpr int NCLASS = 10000;
constexpr int DIM = 512;
constexpr int ROWS_PER_BLOCK = 4;                    // 4 waves/block
constexpr int NBLOCKS = BATCH / ROWS_PER_BLOCK;      // 1024

__global__ __launch_bounds__(256) void center_loss_fused(
    const float* __restrict__ x,
    const float* __restrict__ centers,
    const int* __restrict__ labels,
    double* __restrict__ partial,
    float* __restrict__ out) {
  const int row  = (int)(blockIdx.x * ROWS_PER_BLOCK + (threadIdx.x >> 6));
  const int lane = (int)(threadIdx.x & 63);
  const int widx = (int)(threadIdx.x >> 6);

  __shared__ float  wave_val[ROWS_PER_BLOCK];
  __shared__ double wave_sum[4];

  const int lbl = labels[row];
  const float* __restrict__ xr = x + (size_t)row * DIM;
  const float* __restrict__ cr = centers + (size_t)lbl * DIM;

  float xx = 0.0f, cc = 0.0f, xc = 0.0f;
  // 512 floats / 64 lanes = 8 floats/lane = two float4 chunks, coalesced.
#pragma unroll
  for (int k = 0; k < 2; ++k) {
    const int off = k * 256 + lane * 4;
    const float4 xv = *(const float4*)(xr + off);
    const float4 cv = *(const float4*)(cr + off);
    xx += xv.x * xv.x + xv.y * xv.y + xv.z * xv.z + xv.w * xv.w;
    cc += cv.x * cv.x + cv.y * cv.y + cv.z * cv.z + cv.w * cv.w;
    xc += xv.x * cv.x + xv.y * cv.y + xv.z * cv.z + xv.w * cv.w;
  }
#pragma unroll
  for (int sh = 32; sh > 0; sh >>= 1) {
    xx += __shfl_down(xx, sh, 64);
    cc += __shfl_down(cc, sh, 64);
    xc += __shfl_down(xc, sh, 64);
  }
  float s = 0.5f * (xx + cc) + 0.3f * xc;
  s = fminf(fmaxf(s, 1e-12f), 1e12f);   // clamp AFTER masking, faithful

  if (lane == 0) wave_val[widx] = s;
  __syncthreads();
  if (threadIdx.x == 0) {
    partial[blockIdx.x] = (double)wave_val[0] + (double)wave_val[1] +
                          (double)wave_val[2] + (double)wave_val[3];
  }

  // --- grid-wide barrier: all partial[] stores visible device-wide after this.
  cg::this_grid().sync();

  if (blockIdx.x == 0) {
    const int tid = (int)threadIdx.x;
    // 1024 partials / 256 threads = 4 each (same order as old k2 -> same bits)
    double s2 = partial[tid] + partial[tid + 256] +
                partial[tid + 512] + partial[tid + 768];
#pragma unroll
    for (int sh = 32; sh > 0; sh >>= 1) {
      s2 += __shfl_down(s2, sh, 64);
    }
    if (lane == 0) wave_sum[widx] = s2;
    __syncthreads();
    if (tid == 0) {
      double total = wave_sum[0] + wave_sum[1] + wave_sum[2] + wave_sum[3];
      total += (double)BATCH * (double)(NCLASS - 1) * 1e-12;  // clipped zeros
      out[0] = (float)(total / (double)BATCH);
    }
  }
}

extern "C" void kernel_launch(void* const* d_in, const int* in_sizes, int n_in,
                              void* d_out, int out_size, void* d_ws, size_t ws_size,
                              hipStream_t stream) {
  const float* x       = (const float*)d_in[0];
  const float* centers = (const float*)d_in[1];
  const int*   labels  = (const int*)d_in[2];
  float*       out     = (float*)d_out;
  double*      partial = (double*)d_ws;   // 1024 doubles = 8 KB of ws

  void* args[] = {(void*)&x, (void*)&centers, (void*)&labels,
                  (void*)&partial, (void*)&out};
  hipLaunchCooperativeKernel((const void*)center_loss_fused,
                             dim3(NBLOCKS), dim3(256), args, 0, stream);
}

// Round 2
// 82.382 us; speedup vs baseline: 1.5675x; 1.5675x over previous
//
#include <hip/hip_runtime.h>

// CenterLoss, exact masked shortcut:
//   out = mean_i clip(0.5*(||x_i||^2 + ||c_{l_i}||^2) + 0.3 * x_i . c_{l_i}, 1e-12, 1e12)
//         + (C-1)*1e-12          // the B*(C-1) masked-out zeros, each clipped to 1e-12
// B=4096, C=10000, D=512 (fp32 inputs, int32 labels, fp32 scalar output)
//
// Round-2 lesson: cg::grid.sync() cost ~47us (all-to-all barrier through the
// coherent point; per-XCD L2s non-coherent) -> NEVER full-grid-barrier here.
//
// Round-3 structure: ONE plain kernel, single-node graph.
//   - 1024 blocks x 256 thr, 1 wave per row -> partial[blockIdx] + sentinel
//     flag (device-scope release). Overwrites ws poison; no init, no memset.
//   - block 0 alone polls the 1024 flags (device-scope acquire; one-directional
//     wait, NOT a barrier), then reduces in the exact same order as the old k2
//     kernel -> bit-identical result.
//   Forward progress: producers wait on nothing; finisher's condition is
//   monotone. Stale-flag replay hazard is benign (prior iteration's partials
//   are numerically identical; 8B atomic loads can't tear).
// dur_us is dominated by the harness's 2x256MiB ws poison fills (~68us of the
// 73.3us round-0 total); this removes the k2 node + inter-node gap (~3-4us).

constexpr int BATCH = 4096;
constexpr int NCLASS = 10000;
constexpr int DIM = 512;
constexpr int ROWS_PER_BLOCK = 4;                    // 4 waves/block
constexpr int NBLOCKS = BATCH / ROWS_PER_BLOCK;      // 1024
constexpr unsigned int FLAG_SENTINEL = 0x7F3A9C51u;  // non-repeating bytes:
// can never equal a repeated-byte/word poison fill pattern (0xAA..., 0x55...,
// 0xDEADBEEF, ...), so a poisoned flag never reads as "done".

__global__ __launch_bounds__(256) void center_loss_onepass(
    const float* __restrict__ x,
    const float* __restrict__ centers,
    const int* __restrict__ labels,
    double* __restrict__ partial,
    unsigned int* __restrict__ flags,
    float* __restrict__ out) {
  const int row  = (int)(blockIdx.x * ROWS_PER_BLOCK + (threadIdx.x >> 6));
  const int lane = (int)(threadIdx.x & 63);
  const int widx = (int)(threadIdx.x >> 6);

  __shared__ float  wave_val[ROWS_PER_BLOCK];
  __shared__ double wave_sum[4];

  const int lbl = labels[row];
  const float* __restrict__ xr = x + (size_t)row * DIM;
  const float* __restrict__ cr = centers + (size_t)lbl * DIM;

  float xx = 0.0f, cc = 0.0f, xc = 0.0f;
  // 512 floats / 64 lanes = 8 floats/lane = two float4 chunks, coalesced.
#pragma unroll
  for (int k = 0; k < 2; ++k) {
    const int off = k * 256 + lane * 4;
    const float4 xv = *(const float4*)(xr + off);
    const float4 cv = *(const float4*)(cr + off);
    xx += xv.x * xv.x + xv.y * xv.y + xv.z * xv.z + xv.w * xv.w;
    cc += cv.x * cv.x + cv.y * cv.y + cv.z * cv.z + cv.w * cv.w;
    xc += xv.x * cv.x + xv.y * cv.y + xv.z * cv.z + xv.w * cv.w;
  }
#pragma unroll
  for (int sh = 32; sh > 0; sh >>= 1) {
    xx += __shfl_down(xx, sh, 64);
    cc += __shfl_down(cc, sh, 64);
    xc += __shfl_down(xc, sh, 64);
  }
  float s = 0.5f * (xx + cc) + 0.3f * xc;
  s = fminf(fmaxf(s, 1e-12f), 1e12f);   // clamp AFTER masking, faithful

  if (lane == 0) wave_val[widx] = s;
  __syncthreads();
  if (threadIdx.x == 0) {
    const double p = (double)wave_val[0] + (double)wave_val[1] +
                     (double)wave_val[2] + (double)wave_val[3];
    // Publish: partial first (relaxed), then flag (release) — device scope so
    // the stores are visible across XCDs to the polling block.
    __hip_atomic_store(reinterpret_cast<unsigned long long*>(&partial[blockIdx.x]),
                       __builtin_bit_cast(unsigned long long, p),
                       __ATOMIC_RELAXED, __HIP_MEMORY_SCOPE_AGENT);
    __hip_atomic_store(&flags[blockIdx.x], FLAG_SENTINEL,
                       __ATOMIC_RELEASE, __HIP_MEMORY_SCOPE_AGENT);
  }

  if (blockIdx.x != 0) return;

  // ---- finisher: block 0 only. One-directional wait on 1024 flags.
  const int tid = (int)threadIdx.x;
  double v0, v1, v2, v3;
  {
    // 1024 slots / 256 threads = 4 each; same grouping as the old k2 kernel.
#pragma unroll
    for (int k = 0; k < 4; ++k) {
      const int i = tid + k * 256;
      while (__hip_atomic_load(&flags[i], __ATOMIC_ACQUIRE,
                               __HIP_MEMORY_SCOPE_AGENT) != FLAG_SENTINEL) {
        __builtin_amdgcn_s_sleep(1);
      }
      const double pv = __builtin_bit_cast(double,
          __hip_atomic_load(reinterpret_cast<unsigned long long*>(&partial[i]),
                            __ATOMIC_RELAXED, __HIP_MEMORY_SCOPE_AGENT));
      if (k == 0) v0 = pv; else if (k == 1) v1 = pv;
      else if (k == 2) v2 = pv; else v3 = pv;
    }
  }
  // Same left-to-right order as old k2: partial[tid] + [tid+256] + [tid+512] + [tid+768]
  double s2 = v0 + v1 + v2 + v3;
#pragma unroll
  for (int sh = 32; sh > 0; sh >>= 1) {
    s2 += __shfl_down(s2, sh, 64);
  }
  if (lane == 0) wave_sum[widx] = s2;
  __syncthreads();
  if (tid == 0) {
    double total = wave_sum[0] + wave_sum[1] + wave_sum[2] + wave_sum[3];
    total += (double)BATCH * (double)(NCLASS - 1) * 1e-12;  // clipped zeros
    out[0] = (float)(total / (double)BATCH);
  }
}

extern "C" void kernel_launch(void* const* d_in, const int* in_sizes, int n_in,
                              void* d_out, int out_size, void* d_ws, size_t ws_size,
                              hipStream_t stream) {
  const float* x       = (const float*)d_in[0];
  const float* centers = (const float*)d_in[1];
  const int*   labels  = (const int*)d_in[2];
  float*       out     = (float*)d_out;
  double*      partial = (double*)d_ws;                          // 1024 doubles
  unsigned int* flags  = (unsigned int*)((char*)d_ws + 8192);    // 1024 uints

  center_loss_onepass<<<NBLOCKS, 256, 0, stream>>>(x, centers, labels,
                                                   partial, flags, out);
}

// Round 3
// 72.928 us; speedup vs baseline: 1.7707x; 1.1296x over previous
//
#include <hip/hip_runtime.h>

// CenterLoss, exact masked shortcut:
//   out = mean_i clip(0.5*(||x_i||^2 + ||c_{l_i}||^2) + 0.3 * x_i . c_{l_i}, 1e-12, 1e12)
//         + (C-1)*1e-12          // the B*(C-1) masked-out zeros, each clipped to 1e-12
// B=4096, C=10000, D=512 (fp32 inputs, int32 labels, fp32 scalar output)
//
// Structure: 2 graph nodes, zero initialization requirements.
//   k1: 1024 blocks x 256 thr, 1 wave per row -> partial[blockIdx] (plain store,
//       overwrites the 0xAA poison, no memset needed)
//   k2: 1 block, 256 thr, reduces 1024 partials -> out scalar
//
// SESSION LEDGER (keep — these are measured, do not retry):
//   R0  this structure:                 73.3 us  <- best; fills dominate
//   R1  cg::grid.sync() fusion:        129.1 us  (grid barrier ~47us: all-to-all
//       through the coherent point; per-XCD L2s non-coherent -> never again)
//   R2  flag-poll fusion (AGENT-scope): 82.4 us  (device-scope acquire polling
//       costs more than the 2us k2 node it replaces)
// Floor arithmetic: harness re-poisons ws with 2x256MiB fills at ~76% HBM peak
// (~68-70us, top-5 dispatches every run). k1 reads ~8.2MB (measured FETCH) =
// ~1.5-2.5us at the 6.3TB/s achievable ceiling -> k1 is AT its memory roofline.
// k2 is ~2us pure launch latency. Total tail above fill floor: 3-5us; both
// structural fusion attempts to compress it regressed. This is the roofline.

constexpr int BATCH = 4096;
constexpr int NCLASS = 10000;
constexpr int DIM = 512;
constexpr int ROWS_PER_BLOCK = 4;                    // 4 waves/block
constexpr int NBLOCKS = BATCH / ROWS_PER_BLOCK;      // 1024

__global__ __launch_bounds__(256) void center_loss_rows(
    const float* __restrict__ x,
    const float* __restrict__ centers,
    const int* __restrict__ labels,
    double* __restrict__ partial) {
  const int row  = (int)(blockIdx.x * ROWS_PER_BLOCK + (threadIdx.x >> 6));
  const int lane = (int)(threadIdx.x & 63);
  const int widx = (int)(threadIdx.x >> 6);

  __shared__ float wave_val[ROWS_PER_BLOCK];

  const int lbl = labels[row];
  const float* __restrict__ xr = x + (size_t)row * DIM;
  const float* __restrict__ cr = centers + (size_t)lbl * DIM;

  float xx = 0.0f, cc = 0.0f, xc = 0.0f;
  // 512 floats / 64 lanes = 8 floats/lane = two float4 chunks, coalesced.
#pragma unroll
  for (int k = 0; k < 2; ++k) {
    const int off = k * 256 + lane * 4;
    const float4 xv = *(const float4*)(xr + off);
    const float4 cv = *(const float4*)(cr + off);
    xx += xv.x * xv.x + xv.y * xv.y + xv.z * xv.z + xv.w * xv.w;
    cc += cv.x * cv.x + cv.y * cv.y + cv.z * cv.z + cv.w * cv.w;
    xc += xv.x * cv.x + xv.y * cv.y + xv.z * cv.z + xv.w * cv.w;
  }
#pragma unroll
  for (int sh = 32; sh > 0; sh >>= 1) {
    xx += __shfl_down(xx, sh, 64);
    cc += __shfl_down(cc, sh, 64);
    xc += __shfl_down(xc, sh, 64);
  }
  float s = 0.5f * (xx + cc) + 0.3f * xc;
  s = fminf(fmaxf(s, 1e-12f), 1e12f);   // clamp AFTER masking, faithful

  if (lane == 0) wave_val[widx] = s;
  __syncthreads();
  if (threadIdx.x == 0) {
    partial[blockIdx.x] = (double)wave_val[0] + (double)wave_val[1] +
                          (double)wave_val[2] + (double)wave_val[3];
  }
}

__global__ __launch_bounds__(256) void center_loss_reduce(
    const double* __restrict__ partial,
    float* __restrict__ out) {
  const int tid  = (int)threadIdx.x;
  const int lane = tid & 63;
  const int widx = tid >> 6;

  __shared__ double wave_sum[4];

  // 1024 partials / 256 threads = 4 each
  double s = partial[tid] + partial[tid + 256] +
             partial[tid + 512] + partial[tid + 768];
#pragma unroll
  for (int sh = 32; sh > 0; sh >>= 1) {
    s += __shfl_down(s, sh, 64);
  }
  if (lane == 0) wave_sum[widx] = s;
  __syncthreads();
  if (tid == 0) {
    double total = wave_sum[0] + wave_sum[1] + wave_sum[2] + wave_sum[3];
    total += (double)BATCH * (double)(NCLASS - 1) * 1e-12;  // clipped zeros
    out[0] = (float)(total / (double)BATCH);
  }
}

extern "C" void kernel_launch(void* const* d_in, const int* in_sizes, int n_in,
                              void* d_out, int out_size, void* d_ws, size_t ws_size,
                              hipStream_t stream) {
  const float* x       = (const float*)d_in[0];
  const float* centers = (const float*)d_in[1];
  const int*   labels  = (const int*)d_in[2];
  float*       out     = (float*)d_out;
  double*      partial = (double*)d_ws;   // 1024 doubles = 8 KB of ws

  center_loss_rows<<<NBLOCKS, 256, 0, stream>>>(x, centers, labels, partial);
  center_loss_reduce<<<1, 256, 0, stream>>>(partial, out);
}